// Round 11
// baseline (219.504 us; speedup 1.0000x reference)
//
#include <hip/hip_runtime.h>
#include <math.h>

// Problem constants (B=4, T=2048, C=576, H=12, D=48)
#define Bn 4
#define Tn 2048
#define Cn 576
#define Hn 12
#define Dn 48
#define Mn (Bn*Tn)          // 8192 rows

// log2(e) / sqrt(48) — folded into q so attention uses exp2 directly
#define QSCALE (1.4426950408889634f * 0.14433756729740643f)

typedef short  short8  __attribute__((ext_vector_type(8)));   // 8 bf16 (4 VGPRs)
typedef float  floatx4 __attribute__((ext_vector_type(4)));   // MFMA acc
typedef unsigned short ushort_t;
typedef unsigned short ushort8_t __attribute__((ext_vector_type(8))); // 16B

static __device__ __forceinline__ unsigned short f2bf(float f) {
    union { float f; unsigned int u; } v; v.f = f;
    unsigned int r = v.u + 0x7FFFu + ((v.u >> 16) & 1u);   // round-to-nearest-even
    return (unsigned short)(r >> 16);
}

// truncation-pack two fp32 -> packed bf16x2 (P >= 0, rel err <= 2^-8)
static __device__ __forceinline__ unsigned int pack_trunc(float a, float b) {
    union { float f; unsigned int u; } ua, ub; ua.f = a; ub.f = b;
    return (ua.u >> 16) | (ub.u & 0xFFFF0000u);
}

// async global->LDS, 16B per lane (attention staging only)
static __device__ __forceinline__ void gload16(void* lds, const void* g) {
    __builtin_amdgcn_global_load_lds(
        (const __attribute__((address_space(1))) void*)g,
        (__attribute__((address_space(3))) void*)lds, 16, 0, 0);
}

// ---------------------------------------------------------------------------
// fused fp32 -> bf16 cast of all three inputs (one launch)
// ---------------------------------------------------------------------------
__global__ __launch_bounds__(256)
void cast3(const float* __restrict__ a, ushort_t* __restrict__ oa, int na4,
           const float* __restrict__ b, ushort_t* __restrict__ ob, int nb4,
           const float* __restrict__ c, ushort_t* __restrict__ oc, int nc4)
{
    int i = blockIdx.x * 256 + threadIdx.x;
    const float* src; ushort_t* dst; int idx;
    if (i < na4)                  { src = a; dst = oa; idx = i; }
    else if (i < na4 + nb4)       { src = b; dst = ob; idx = i - na4; }
    else if (i < na4 + nb4 + nc4) { src = c; dst = oc; idx = i - na4 - nb4; }
    else return;
    float4 v = ((const float4*)src)[idx];
    ushort4 o;
    o.x = f2bf(v.x); o.y = f2bf(v.y); o.z = f2bf(v.z); o.w = f2bf(v.w);
    ((ushort4*)dst)[idx] = o;
}

// ---------------------------------------------------------------------------
// MFMA bf16 GEMM, DIRECT-REGISTER K-loop (AITER/hipBLASLt structure):
// out = A[M,576] @ W[N,576]^T.  NO LDS and NO barriers in the main loop —
// A/B fragments are loaded straight from global into VGPRs (the MFMA frag
// pattern is 16 full 64B sectors per load inst). 2-stage register pipeline
// with alternating buffers (bounds hoisting -> no spill); compiler emits
// precise vmcnt(N) from register deps, loads stay in flight.
// Each wave owns an independent 64x64 tile; block = 4 waves stacked in M
// (the 4 waves share W-frag addresses -> L1 hits). XCD swizzle: all NB
// n-blocks of one m-group on one XCD -> A ~once from HBM, W L2-resident.
// Epilogue (MODE 0): wave-private LDS restage (no barrier, lgkm wait only)
// -> coalesced 16B-chunk writes (q/k row-major; v transposed to [B,H,48,T]).
// MODE 1: fp32 row-major direct.
// ---------------------------------------------------------------------------
template<int MODE>
__global__ __launch_bounds__(256, 2)
void gemm_mfma(const ushort_t* __restrict__ A, const ushort_t* __restrict__ W,
               ushort_t* __restrict__ outb, float* __restrict__ outf)
{
    constexpr int NB    = (MODE == 0) ? 27 : 9;
    constexpr int NSTEP = Cn / 32;             // 18
    __shared__ __align__(16) ushort_t Ep[4][64 * 72];   // 36 KB epilogue staging

    const int tid  = threadIdx.x;
    const int wave = tid >> 6;
    const int lane = tid & 63;
    const int m    = lane & 15;
    const int g    = lane >> 4;
    const int bid  = blockIdx.x;
    const int xcd  = bid & 7;
    const int slot = bid >> 3;
    const int n0   = (slot % NB) * 64;
    const int m0   = (xcd + 8 * (slot / NB)) * 256;
    const int mw   = m0 + wave * 64;           // this wave's 64-row tile

    // per-lane fragment base pointers (advance via immediate offsets)
    const ushort_t* pa[4];
    const ushort_t* pb[4];
    #pragma unroll
    for (int i = 0; i < 4; ++i) {
        pa[i] = A + (size_t)(mw + i * 16 + m) * Cn + g * 8;
        pb[i] = W + (size_t)(n0 + i * 16 + m) * Cn + g * 8;
    }

    floatx4 acc[4][4];
    #pragma unroll
    for (int i = 0; i < 4; ++i)
        #pragma unroll
        for (int j = 0; j < 4; ++j)
            acc[i][j] = (floatx4){0.f, 0.f, 0.f, 0.f};

    short8 fa[2][4], fb[2][4];
    #pragma unroll
    for (int i = 0; i < 4; ++i) { fa[0][i] = *(const short8*)pa[i];
                                  fb[0][i] = *(const short8*)pb[i]; }

    #pragma unroll
    for (int k = 0; k < NSTEP; ++k) {
        const int c = k & 1;
        if (k + 1 < NSTEP) {        // prefetch next K-step into the other buffer
            #pragma unroll
            for (int i = 0; i < 4; ++i) {
                fa[c ^ 1][i] = *(const short8*)(pa[i] + (k + 1) * 32);
                fb[c ^ 1][i] = *(const short8*)(pb[i] + (k + 1) * 32);
            }
        }
        #pragma unroll
        for (int i = 0; i < 4; ++i)
            #pragma unroll
            for (int j = 0; j < 4; ++j)
                acc[i][j] = __builtin_amdgcn_mfma_f32_16x16x32_bf16(fa[c][i], fb[c][j], acc[i][j], 0, 0, 0);
    }

    // ---- epilogue: C/D col = lane&15 (n), row = (lane>>4)*4 + reg (m) ----
    const size_t per = (size_t)Bn * Hn * Tn * Dn;
    if (MODE == 0) {
        const int which = n0 / Cn;
        const int nb    = n0 - which * Cn;
        const int b     = mw >> 11;            // 64 | 2048 -> no batch straddle
        const int t0w   = mw & 2047;
        ushort_t* Lw = &Ep[wave][0];           // wave-private strip
        if (which == 2) {
            // stage transposed: Lw[col(64)][row(64)], stride 72 (16B-aligned rows)
            #pragma unroll
            for (int i = 0; i < 4; ++i)
                #pragma unroll
                for (int j = 0; j < 4; ++j) {
                    ushort4 pk;
                    pk.x = f2bf(acc[i][j][0]); pk.y = f2bf(acc[i][j][1]);
                    pk.z = f2bf(acc[i][j][2]); pk.w = f2bf(acc[i][j][3]);
                    *(ushort4*)&Lw[(j * 16 + m) * 72 + i * 16 + g * 4] = pk;
                }
            asm volatile("s_waitcnt lgkmcnt(0)" ::: "memory");
            // write [B,H,48,T]: 16B = 8 consecutive t
            #pragma unroll
            for (int it = 0; it < 8; ++it) {
                int c    = it * 64 + lane;
                int col  = c >> 3;
                int rowc = (c & 7) * 8;
                int n    = nb + col;
                int h    = n / 48;
                int d    = n - h * 48;
                ushort_t* dst = outb + 2 * per
                    + (((size_t)(b * Hn + h) * Dn + d) * Tn) + t0w + rowc;
                *(ushort8_t*)dst = *(const ushort8_t*)&Lw[col * 72 + rowc];
            }
        } else {
            const float sc = (which == 0) ? QSCALE : 1.0f;
            // stage row-major: Lw[row(64)][col(64)], stride 72
            #pragma unroll
            for (int i = 0; i < 4; ++i)
                #pragma unroll
                for (int j = 0; j < 4; ++j)
                    #pragma unroll
                    for (int r = 0; r < 4; ++r)
                        Lw[(i * 16 + g * 4 + r) * 72 + j * 16 + m] =
                            f2bf(acc[i][j][r] * sc);
            asm volatile("s_waitcnt lgkmcnt(0)" ::: "memory");
            // write [B,H,T,48]: 16B chunks never straddle a head (8 | 48)
            #pragma unroll
            for (int it = 0; it < 8; ++it) {
                int c   = it * 64 + lane;
                int row = c >> 3;
                int c8  = (c & 7) * 8;
                int n   = nb + c8;
                int h   = n / 48;
                int d   = n - h * 48;
                ushort_t* dst = outb + (size_t)which * per
                    + (((size_t)(b * Hn + h) * Tn + t0w + row) * Dn) + d;
                *(ushort8_t*)dst = *(const ushort8_t*)&Lw[row * 72 + c8];
            }
        }
    } else {
        #pragma unroll
        for (int i = 0; i < 4; ++i) {
            #pragma unroll
            for (int r = 0; r < 4; ++r) {
                int mrow = mw + i * 16 + g * 4 + r;
                #pragma unroll
                for (int j = 0; j < 4; ++j)
                    outf[(size_t)mrow * Cn + n0 + j * 16 + m] = acc[i][j][r];
            }
        }
    }
}

// ---------------------------------------------------------------------------
// Flash attention via S^T, no-max softmax, bf16 MFMA (round-10 kernel,
// unchanged: interleaved-qt grid, Q-tile 128, 512 thr, global_load_lds
// double-buffer, Ps aliases dead Q strip).
// ---------------------------------------------------------------------------
__global__ __launch_bounds__(512, 6)
void attn_mfma(const ushort_t* __restrict__ Q, const ushort_t* __restrict__ K,
               const ushort_t* __restrict__ V, ushort_t* __restrict__ Y,
               const ushort_t* __restrict__ zb)
{
    __shared__ __align__(16) ushort_t QPs[16][512];    // Q tile, then reused as P^T
    __shared__ __align__(16) ushort_t Ks[2][8][512];   // [buf][(ktile t, kc)]
    __shared__ __align__(16) ushort_t Vs[2][6][512];   // [buf][(dtile t, kc)]

    const int id   = blockIdx.x;
    const int kk   = id / 48;
    const int bh   = id - kk * 48;
    const int QT   = (kk & 1) ? (kk >> 1) : (15 - (kk >> 1));   // interleave big/small
    const int tid  = threadIdx.x;
    const int wave = tid >> 6;       // 0..7
    const int lane = tid & 63;
    const int m    = lane & 15;
    const int g    = lane >> 4;
    const int q0   = QT * 128;
    const int nkt  = 2 * QT + 2;     // 64-row K tiles to process

    const ushort_t* Qp = Q + (size_t)bh * Tn * Dn;
    const ushort_t* Kp = K + (size_t)bh * Tn * Dn;
    const ushort_t* Vp = V + (size_t)bh * Dn * Tn;     // [48][T]

    // ---- Q staging: wave w stages segs 2w,2w+1 (rows q0+w*16+m); pad -> zeros ----
    {
        const char* qrp = (const char*)(Qp + (size_t)(q0 + wave * 16 + m) * Dn);
        gload16(&QPs[wave * 2 + 0][0], qrp + g * 16);
        gload16(&QPs[wave * 2 + 1][0], (g < 2) ? (qrp + 64 + g * 16) : (const char*)zb);
    }

    // ---- per-lane K/V staging pointers (wave w owns K seg w; V seg w for w<6) ----
    const bool  kpad = ((wave & 1) == 1) && (g >= 2);
    const char* kptr = kpad ? (const char*)zb
        : (const char*)(Kp + (size_t)((wave >> 1) * 16 + m) * Dn) + (wave & 1) * 64 + g * 16;
    const int   kadv = kpad ? 0 : 64 * Dn * 2;         // 64 K-rows per tile
    const char* vptr = (const char*)(Vp + (size_t)((wave >> 1) * 16 + m) * Tn)
                       + (wave & 1) * 64 + g * 16;     // valid only for wave<6
    const int   vadv = 64 * 2;                         // 64 V^T-cols per tile

    // prologue: stage K/V tile 0 into buf 0
    gload16(&Ks[0][wave][0], kptr); kptr += kadv;
    if (wave < 6) { gload16(&Vs[0][wave][0], vptr); vptr += vadv; }
    __syncthreads();   // drains vmcnt -> Q + tile0 ready

    // loop-invariant B-fragments (Q); QPs strip (wave-private) then dead -> P^T
    short8 bq[2];
    bq[0] = *(const short8*)&QPs[wave * 2 + 0][lane * 8];
    bq[1] = *(const short8*)&QPs[wave * 2 + 1][lane * 8];

    floatx4 acc[3];
    #pragma unroll
    for (int t = 0; t < 3; ++t) acc[t] = (floatx4){0.f, 0.f, 0.f, 0.f};
    float l_tot = 0.f;
    const int qrow  = q0 + wave * 16 + m;    // this lane's global query row
    const int qwmin = q0 + wave * 16;        // wave's min query row
    const int qwmax = qwmin + 15;            // wave's max query row

    for (int jt = 0; jt < nkt; ++jt) {
        const int cur = jt & 1;
        const int j0  = jt * 64;
        // issue async staging for tile jt+1 (overlaps this tile's compute)
        if (jt + 1 < nkt) {
            gload16(&Ks[cur ^ 1][wave][0], kptr); kptr += kadv;
            if (wave < 6) { gload16(&Vs[cur ^ 1][wave][0], vptr); vptr += vadv; }
        }

        if (j0 <= qwmax) {   // wave-uniform: at least one unmasked element
            // ---- S^T = K Q^T : D[m=j (4 tiles)][n=q] ----
            floatx4 s[4];
            #pragma unroll
            for (int t = 0; t < 4; ++t) {
                s[t] = (floatx4){0.f, 0.f, 0.f, 0.f};
                #pragma unroll
                for (int kc = 0; kc < 2; ++kc) {
                    short8 ak = *(const short8*)&Ks[cur][t * 2 + kc][lane * 8];
                    s[t] = __builtin_amdgcn_mfma_f32_16x16x32_bf16(ak, bq[kc], s[t], 0, 0, 0);
                }
            }

            // ---- mask (only if tile straddles diagonal) + exp2 + partial sum ----
            float p[4][4];
            float lsum = 0.f;
            if (j0 + 63 > qwmin) {
                #pragma unroll
                for (int t = 0; t < 4; ++t)
                    #pragma unroll
                    for (int r = 0; r < 4; ++r) {
                        int j = j0 + t * 16 + g * 4 + r;
                        float v = (j <= qrow) ? s[t][r] : -1e30f;
                        float e = __builtin_amdgcn_exp2f(v);
                        p[t][r] = e; lsum += e;
                    }
            } else {
                #pragma unroll
                for (int t = 0; t < 4; ++t)
                    #pragma unroll
                    for (int r = 0; r < 4; ++r) {
                        float e = __builtin_amdgcn_exp2f(s[t][r]);
                        p[t][r] = e; lsum += e;
                    }
            }
            lsum += __shfl_xor(lsum, 16);
            lsum += __shfl_xor(lsum, 32);
            l_tot += lsum;

            // ---- store P^T in B-frag order into the (dead) Q strip ----
            #pragma unroll
            for (int t = 0; t < 4; ++t) {
                uint2 w2;
                w2.x = pack_trunc(p[t][0], p[t][1]);
                w2.y = pack_trunc(p[t][2], p[t][3]);
                *(uint2*)&QPs[wave * 2 + (t >> 1)]
                             [(2 * (t & 1) + (g >> 1)) * 128 + m * 8 + (g & 1) * 4] = w2;
            }
            // wave-private strip: drain this wave's LDS writes, no barrier needed
            asm volatile("s_waitcnt lgkmcnt(0)" ::: "memory");

            // ---- O^T += V^T P^T : D[m=d (3 tiles)][n=q] ----
            #pragma unroll
            for (int kc = 0; kc < 2; ++kc) {
                short8 bp = *(const short8*)&QPs[wave * 2 + kc][lane * 8];
                #pragma unroll
                for (int t = 0; t < 3; ++t) {
                    short8 av = *(const short8*)&Vs[cur][t * 2 + kc][lane * 8];
                    acc[t] = __builtin_amdgcn_mfma_f32_16x16x32_bf16(av, bp, acc[t], 0, 0, 0);
                }
            }
        }

        __syncthreads();   // next tile staged (vmcnt drain) + cur-buf reads done
    }

    // ---- epilogue: lane holds O^T[d = t*16+g*4+r][qrow]; normalize, store ----
    const float inv = 1.0f / l_tot;
    const int b = bh / Hn;
    const int h = bh - b * Hn;
    ushort_t* yp = Y + ((size_t)(b * Tn + qrow)) * Cn + h * Dn;
    #pragma unroll
    for (int t = 0; t < 3; ++t) {
        ushort4 o;
        o.x = f2bf(acc[t][0] * inv);
        o.y = f2bf(acc[t][1] * inv);
        o.z = f2bf(acc[t][2] * inv);
        o.w = f2bf(acc[t][3] * inv);
        *(ushort4*)&yp[t * 16 + g * 4] = o;
    }
}

// ---------------------------------------------------------------------------
extern "C" void kernel_launch(void* const* d_in, const int* in_sizes, int n_in,
                              void* d_out, int out_size, void* d_ws, size_t ws_size,
                              hipStream_t stream)
{
    const float* x      = (const float*)d_in[0];   // [B,T,C]
    const float* w_qkv  = (const float*)d_in[1];   // [3C,C]
    const float* w_proj = (const float*)d_in[2];   // [C,C]
    float* out = (float*)d_out;                    // [B,T,C] fp32

    const size_t per = (size_t)Bn * Hn * Tn * Dn;  // 4,718,592

    ushort_t* xb  = (ushort_t*)d_ws;               // 8192*576
    ushort_t* wqb = xb  + (size_t)Mn * Cn;         // 1728*576
    ushort_t* wpb = wqb + (size_t)3 * Cn * Cn;     // 576*576
    ushort_t* qkv = wpb + (size_t)Cn * Cn;         // 3*per (q | k | v^T)
    ushort_t* yb  = qkv + 3 * per;                 // 8192*576
    ushort_t* zb  = yb  + (size_t)Mn * Cn;         // 256 B of zeros (Q/K pad source)

    hipMemsetAsync(zb, 0, 256, stream);

    // fused casts (fp32 -> bf16)
    const int na4 = Mn * Cn / 4, nb4 = 3 * Cn * Cn / 4, nc4 = Cn * Cn / 4;
    cast3<<<dim3((na4 + nb4 + nc4 + 255) / 256), dim3(256), 0, stream>>>(
        x, xb, na4, w_qkv, wqb, nb4, w_proj, wpb, nc4);

    // QKV GEMM (M=8192, N=1728): 864 blocks = 8 XCD x (4 m-groups x 27 n)
    gemm_mfma<0><<<dim3((Mn / 256) * 27), dim3(256), 0, stream>>>(xb, wqb, qkv, nullptr);

    // causal attention (ALiBi bias is exactly zero on the unmasked region)
    attn_mfma<<<dim3((Tn / 128) * Bn * Hn), dim3(512), 0, stream>>>(
        qkv, qkv + per, qkv + 2 * per, yb, zb);

    // output projection (M=8192, N=576) -> fp32: 288 blocks = 8 x (4 x 9)
    gemm_mfma<1><<<dim3((Mn / 256) * 9), dim3(256), 0, stream>>>(yb, wpb, nullptr, out);
}